// Round 3
// baseline (180.161 us; speedup 1.0000x reference)
//
#include <hip/hip_runtime.h>
#include <hip/hip_bf16.h>
#include <stdint.h>
#include <stddef.h>

#define BATCH 256
#define OC 4096
#define IC 4096
#define VALUE_SCALE 0.1f

#define BN 128          // N-tile (output features per WG)
#define BK 32           // K-step (fp32 words)
#define KS 8            // split-K factor; ks = bid&7 pins K-slice to one XCD
#define KPER (IC / KS)  // 512
#define NT (KPER / BK)  // 16 K-steps

typedef float f32x4 __attribute__((ext_vector_type(4)));
typedef int   i32x4 __attribute__((ext_vector_type(4)));
typedef short bf16x8 __attribute__((ext_vector_type(8)));

// ---------------- scatter: w[idx[i]] = val[i] * 0.1 (set; idempotent) ----------------
// nontemporal stores: skip L2 write-allocate line fetch for random 4B stores.
__global__ void scatter_k(float* __restrict__ w, const int* __restrict__ idx,
                          const float* __restrict__ val, int n) {
    int i = (blockIdx.x * blockDim.x + threadIdx.x) * 4;
    if (i + 4 <= n) {
        i32x4 id = *(const i32x4*)(idx + i);
        f32x4 v  = *(const f32x4*)(val + i);
        __builtin_nontemporal_store(v[0] * VALUE_SCALE, &w[id[0]]);
        __builtin_nontemporal_store(v[1] * VALUE_SCALE, &w[id[1]]);
        __builtin_nontemporal_store(v[2] * VALUE_SCALE, &w[id[2]]);
        __builtin_nontemporal_store(v[3] * VALUE_SCALE, &w[id[3]]);
    } else {
        for (int j = i; j < n; ++j) w[idx[j]] = val[j] * VALUE_SCALE;
    }
}

__device__ __forceinline__ void gload16(const float* src, float* ldsDst) {
    __builtin_amdgcn_global_load_lds(
        (const __attribute__((address_space(1))) void*)src,
        (__attribute__((address_space(3))) void*)ldsDst, 16, 0, 0);
}

__device__ __forceinline__ short f2bf_rn(float f) {
    return (short)__bfloat16_as_ushort(__float2bfloat16(f));
}

// ---------------- split-K bf16 GEMM: y[m,n] += sum_k x[m,k]*w[n,k] ----------------
// grid = 256 (1 WG/CU): ks = bid&7 (XCD-pinned K-slice), bn = bid>>3 (N-tile).
// 512 thr = 8 waves (2/SIMD), wave grid 4m x 2n, wave tile 64x64 = 4x4 frags of 16x16.
// LDS 96KB: double-buffered fp32 tiles via async global_load_lds; fp32->bf16 at frag read.
// Chunk swizzle: 16B chunk c of row stored at slot c^(row&7) (applied on global SOURCE
// address since global_load_lds writes linearly — rule #21).
__global__ __launch_bounds__(512, 2) void gemm_k(const float* __restrict__ x,
                                                 const float* __restrict__ w,
                                                 float* __restrict__ y) {
    const int tid  = threadIdx.x;
    const int lane = tid & 63;
    const int wv   = tid >> 6;      // 0..7
    const int wvm  = wv >> 1;       // 0..3 -> rows wvm*64..+64
    const int wvn  = wv & 1;        // 0..1 -> cols wvn*64..+64
    const int bid  = blockIdx.x;
    const int ks   = bid & 7;
    const int bn   = bid >> 3;
    const int k0   = ks * KPER;
    const int nc0  = bn * BN;

    __shared__ __align__(16) float At[2][BATCH * BK];  // 2 x 32KB
    __shared__ __align__(16) float Bt[2][BN * BK];     // 2 x 16KB  -> 96KB total

    f32x4 acc[4][4];
#pragma unroll
    for (int m = 0; m < 4; ++m)
#pragma unroll
        for (int n = 0; n < 4; ++n) acc[m][n] = (f32x4)0.0f;

    // async stage of K-step t into buffer buf: 6 global_load_lds_dwordx4 per wave
    auto stage = [&](int buf, int t) {
        const int kg = k0 + t * BK;
        const int rsub = lane >> 3;          // 0..7 (row within 8-row group)
        const int csl  = lane & 7;           // lds chunk slot 0..7
#pragma unroll
        for (int j = 0; j < 4; ++j) {        // A: rows wv*32 .. +32
            int r0  = wv * 32 + j * 8;
            int row = r0 + rsub;
            int c   = csl ^ (row & 7);       // global chunk for this lds slot
            gload16(x + (size_t)row * IC + kg + c * 4, &At[buf][r0 * BK]);
        }
#pragma unroll
        for (int j = 0; j < 2; ++j) {        // B: rows wv*16 .. +16
            int r0  = wv * 16 + j * 8;
            int row = r0 + rsub;
            int c   = csl ^ (row & 7);
            gload16(w + (size_t)(nc0 + row) * IC + kg + c * 4, &Bt[buf][r0 * BK]);
        }
    };

    // read one 16x16x32 A/B fragment from swizzled fp32 LDS, convert to bf16
    auto readFrag = [&](const float* tile, int row) -> bf16x8 {
        int c0  = (lane >> 4) * 2;           // logical chunk pair (k-words c0*4..c0*4+8)
        int cp0 = c0 ^ (row & 7);
        int cp1 = (c0 + 1) ^ (row & 7);
        const float* base = tile + row * BK;
        f32x4 lo = *(const f32x4*)(base + cp0 * 4);
        f32x4 hi = *(const f32x4*)(base + cp1 * 4);
        bf16x8 r;
#pragma unroll
        for (int j = 0; j < 4; ++j) {
            r[j]     = f2bf_rn(lo[j]);
            r[j + 4] = f2bf_rn(hi[j]);
        }
        return r;
    };

    // prologue
    stage(0, 0);
    __syncthreads();   // compiler emits vmcnt(0) drain before s_barrier

    for (int t = 0; t < NT; ++t) {
        const int cur = t & 1;
        if (t + 1 < NT) stage(cur ^ 1, t + 1);   // async loads fly under compute

        bf16x8 a[4], b[4];
#pragma unroll
        for (int m = 0; m < 4; ++m)
            a[m] = readFrag(At[cur], wvm * 64 + m * 16 + (lane & 15));
#pragma unroll
        for (int n = 0; n < 4; ++n)
            b[n] = readFrag(Bt[cur], wvn * 64 + n * 16 + (lane & 15));
#pragma unroll
        for (int n = 0; n < 4; ++n)
#pragma unroll
            for (int m = 0; m < 4; ++m)
                acc[m][n] = __builtin_amdgcn_mfma_f32_16x16x32_bf16(a[m], b[n], acc[m][n], 0, 0, 0);

        __syncthreads();   // drains vmcnt (next-tile loads landed) + lds reads done
    }

    // epilogue: C/D layout col=lane&15, row=(lane>>4)*4+reg  [m89, proven R1]
#pragma unroll
    for (int m = 0; m < 4; ++m) {
        int r0 = wvm * 64 + m * 16 + (lane >> 4) * 4;
#pragma unroll
        for (int n = 0; n < 4; ++n) {
            int c = nc0 + wvn * 64 + n * 16 + (lane & 15);
#pragma unroll
            for (int r = 0; r < 4; ++r)
                atomicAdd(&y[(size_t)(r0 + r) * OC + c], acc[m][n][r]);
        }
    }
}

extern "C" void kernel_launch(void* const* d_in, const int* in_sizes, int n_in,
                              void* d_out, int out_size, void* d_ws, size_t ws_size,
                              hipStream_t stream) {
    const float* x  = (const float*)d_in[0];
    float*       w  = (float*)d_in[1];      // scattered in place (set = idempotent)
    const int*   fi = (const int*)d_in[2];
    const float* fv = (const float*)d_in[3];
    float*       y  = (float*)d_out;
    const int nflip = in_sizes[2];

    hipMemsetAsync(d_out, 0, (size_t)out_size * sizeof(float), stream);
    scatter_k<<<dim3((nflip + 1023) / 1024), dim3(256), 0, stream>>>(w, fi, fv, nflip);
    gemm_k<<<dim3(32 * KS), dim3(512), 0, stream>>>(x, w, y);
}

// Round 4
// 153.109 us; speedup vs baseline: 1.1767x; 1.1767x over previous
//
#include <hip/hip_runtime.h>
#include <hip/hip_bf16.h>
#include <stdint.h>
#include <stddef.h>

#define BATCH 256
#define OC 4096
#define IC 4096
#define VALUE_SCALE 0.1f

#define BN 128          // N-tile (output features per WG)
#define BK 32           // K-step (fp32 words)
#define KS 8            // split-K factor; ks = bid&7 pins K-slice to one XCD
#define KPER (IC / KS)  // 512
#define NT (KPER / BK)  // 16 K-steps
#define YSZ (BATCH * OC)  // 1M floats = 4MB

typedef float f32x4 __attribute__((ext_vector_type(4)));
typedef int   i32x4 __attribute__((ext_vector_type(4)));
typedef short bf16x8 __attribute__((ext_vector_type(8)));

// ---------------- scatter: w[idx[i]] = val[i] * 0.1 (set; idempotent) ----------------
// plain stores (R3: nontemporal regressed +16us total — reverted)
__global__ void scatter_k(float* __restrict__ w, const int* __restrict__ idx,
                          const float* __restrict__ val, int n) {
    int i = (blockIdx.x * blockDim.x + threadIdx.x) * 4;
    if (i + 4 <= n) {
        i32x4 id = *(const i32x4*)(idx + i);
        f32x4 v  = *(const f32x4*)(val + i);
        w[id[0]] = v[0] * VALUE_SCALE;
        w[id[1]] = v[1] * VALUE_SCALE;
        w[id[2]] = v[2] * VALUE_SCALE;
        w[id[3]] = v[3] * VALUE_SCALE;
    } else {
        for (int j = i; j < n; ++j) w[idx[j]] = val[j] * VALUE_SCALE;
    }
}

__device__ __forceinline__ void gload16(const float* src, float* ldsDst) {
    __builtin_amdgcn_global_load_lds(
        (const __attribute__((address_space(1))) void*)src,
        (__attribute__((address_space(3))) void*)ldsDst, 16, 0, 0);
}

__device__ __forceinline__ short f2bf_rn(float f) {
    return (short)__bfloat16_as_ushort(__float2bfloat16(f));
}

// ---------------- split-K bf16 GEMM: part[ks] = x @ W[ncols]^T (K-slice ks) --------
// grid = 256 (1 WG/CU): ks = bid&7 (XCD-pinned K-slice), bn = bid>>3 (N-tile).
// 512 thr = 8 waves (2/SIMD), wave grid 4m x 2n, wave tile 64x64 = 4x4 frags of 16x16.
// LDS 96KB: double-buffered fp32 tiles via async global_load_lds; fp32->bf16 at frag read.
// Chunk swizzle on global SOURCE address (linear LDS dest — rule #21).
// Epilogue: plain stores to per-slice partial buffer (R3 post-mortem: 8.4M cross-XCD
// atomicAdds dominated at ~55us — WRITE_SIZE showed zero coalescing).
__global__ __launch_bounds__(512, 2) void gemm_k(const float* __restrict__ x,
                                                 const float* __restrict__ w,
                                                 float* __restrict__ part,
                                                 float* __restrict__ y) {
    const int tid  = threadIdx.x;
    const int lane = tid & 63;
    const int wv   = tid >> 6;      // 0..7
    const int wvm  = wv >> 1;       // 0..3 -> rows wvm*64..+64
    const int wvn  = wv & 1;        // 0..1 -> cols wvn*64..+64
    const int bid  = blockIdx.x;
    const int ks   = bid & 7;
    const int bn   = bid >> 3;
    const int k0   = ks * KPER;
    const int nc0  = bn * BN;

    __shared__ __align__(16) float At[2][BATCH * BK];  // 2 x 32KB
    __shared__ __align__(16) float Bt[2][BN * BK];     // 2 x 16KB  -> 96KB total

    f32x4 acc[4][4];
#pragma unroll
    for (int m = 0; m < 4; ++m)
#pragma unroll
        for (int n = 0; n < 4; ++n) acc[m][n] = (f32x4)0.0f;

    auto stage = [&](int buf, int t) {
        const int kg = k0 + t * BK;
        const int rsub = lane >> 3;          // 0..7 (row within 8-row group)
        const int csl  = lane & 7;           // lds chunk slot 0..7
#pragma unroll
        for (int j = 0; j < 4; ++j) {        // A: rows wv*32 .. +32
            int r0  = wv * 32 + j * 8;
            int row = r0 + rsub;
            int c   = csl ^ (row & 7);       // global chunk for this lds slot
            gload16(x + (size_t)row * IC + kg + c * 4, &At[buf][r0 * BK]);
        }
#pragma unroll
        for (int j = 0; j < 2; ++j) {        // B: rows wv*16 .. +16
            int r0  = wv * 16 + j * 8;
            int row = r0 + rsub;
            int c   = csl ^ (row & 7);
            gload16(w + (size_t)(nc0 + row) * IC + kg + c * 4, &Bt[buf][r0 * BK]);
        }
    };

    auto readFrag = [&](const float* tile, int row) -> bf16x8 {
        int c0  = (lane >> 4) * 2;           // logical chunk pair
        int cp0 = c0 ^ (row & 7);
        int cp1 = (c0 + 1) ^ (row & 7);
        const float* base = tile + row * BK;
        f32x4 lo = *(const f32x4*)(base + cp0 * 4);
        f32x4 hi = *(const f32x4*)(base + cp1 * 4);
        bf16x8 r;
#pragma unroll
        for (int j = 0; j < 4; ++j) {
            r[j]     = f2bf_rn(lo[j]);
            r[j + 4] = f2bf_rn(hi[j]);
        }
        return r;
    };

    stage(0, 0);
    __syncthreads();

    for (int t = 0; t < NT; ++t) {
        const int cur = t & 1;
        if (t + 1 < NT) stage(cur ^ 1, t + 1);

        bf16x8 a[4], b[4];
#pragma unroll
        for (int m = 0; m < 4; ++m)
            a[m] = readFrag(At[cur], wvm * 64 + m * 16 + (lane & 15));
#pragma unroll
        for (int n = 0; n < 4; ++n)
            b[n] = readFrag(Bt[cur], wvn * 64 + n * 16 + (lane & 15));
#pragma unroll
        for (int n = 0; n < 4; ++n)
#pragma unroll
            for (int m = 0; m < 4; ++m)
                acc[m][n] = __builtin_amdgcn_mfma_f32_16x16x32_bf16(a[m], b[n], acc[m][n], 0, 0, 0);

        __syncthreads();
    }

    // epilogue: C/D layout col=lane&15, row=(lane>>4)*4+reg  [proven R1/R3]
    if (part) {
        float* dst = part + (size_t)ks * YSZ;
#pragma unroll
        for (int m = 0; m < 4; ++m) {
            int r0 = wvm * 64 + m * 16 + (lane >> 4) * 4;
#pragma unroll
            for (int n = 0; n < 4; ++n) {
                int c = nc0 + wvn * 64 + n * 16 + (lane & 15);
#pragma unroll
                for (int r = 0; r < 4; ++r)
                    dst[(size_t)(r0 + r) * OC + c] = acc[m][n][r];
            }
        }
    } else {  // fallback when ws too small: old atomic path (y pre-zeroed)
#pragma unroll
        for (int m = 0; m < 4; ++m) {
            int r0 = wvm * 64 + m * 16 + (lane >> 4) * 4;
#pragma unroll
            for (int n = 0; n < 4; ++n) {
                int c = nc0 + wvn * 64 + n * 16 + (lane & 15);
#pragma unroll
                for (int r = 0; r < 4; ++r)
                    atomicAdd(&y[(size_t)(r0 + r) * OC + c], acc[m][n][r]);
            }
        }
    }
}

// ---------------- reduce: y = sum of KS partial buffers (streaming, f32x4) ----------
__global__ void reduce_k(const float* __restrict__ part, float* __restrict__ y) {
    int i = (blockIdx.x * blockDim.x + threadIdx.x) * 4;
    f32x4 s = *(const f32x4*)(part + i);
#pragma unroll
    for (int p = 1; p < KS; ++p) s += *(const f32x4*)(part + (size_t)p * YSZ + i);
    *(f32x4*)(y + i) = s;
}

extern "C" void kernel_launch(void* const* d_in, const int* in_sizes, int n_in,
                              void* d_out, int out_size, void* d_ws, size_t ws_size,
                              hipStream_t stream) {
    const float* x  = (const float*)d_in[0];
    float*       w  = (float*)d_in[1];      // scattered in place (set = idempotent)
    const int*   fi = (const int*)d_in[2];
    const float* fv = (const float*)d_in[3];
    float*       y  = (float*)d_out;
    const int nflip = in_sizes[2];

    const bool use_ws = ws_size >= (size_t)KS * YSZ * sizeof(float);  // 32MB
    float* part = use_ws ? (float*)d_ws : nullptr;

    if (!use_ws) hipMemsetAsync(d_out, 0, (size_t)out_size * sizeof(float), stream);
    scatter_k<<<dim3((nflip + 1023) / 1024), dim3(256), 0, stream>>>(w, fi, fv, nflip);
    gemm_k<<<dim3(32 * KS), dim3(512), 0, stream>>>(x, w, part, y);
    if (use_ws)
        reduce_k<<<dim3(YSZ / (4 * 256)), dim3(256), 0, stream>>>(part, y);
}

// Round 6
// 152.521 us; speedup vs baseline: 1.1812x; 1.0039x over previous
//
#include <hip/hip_runtime.h>
#include <hip/hip_bf16.h>
#include <stdint.h>
#include <stddef.h>

#define BATCH 256
#define OC 4096
#define IC 4096
#define VALUE_SCALE 0.1f

#define BN 64           // N-tile (output features per WG)  [R5: 128->64 for 2 WG/CU]
#define BK 32           // K-step (fp32 words)
#define KS 8            // split-K factor; ks = bid&7 pins K-slice to one XCD
#define KPER (IC / KS)  // 512
#define NT (KPER / BK)  // 16 K-steps
#define YSZ (BATCH * OC)  // 1M floats = 4MB

typedef float f32x4 __attribute__((ext_vector_type(4)));
typedef int   i32x4 __attribute__((ext_vector_type(4)));
typedef short bf16x8 __attribute__((ext_vector_type(8)));

// ---------------- scatter: w[idx[i]] = val[i] * 0.1 (set; idempotent) ----------------
__global__ void scatter_k(float* __restrict__ w, const int* __restrict__ idx,
                          const float* __restrict__ val, int n) {
    int i = (blockIdx.x * blockDim.x + threadIdx.x) * 4;
    if (i + 4 <= n) {
        i32x4 id = *(const i32x4*)(idx + i);
        f32x4 v  = *(const f32x4*)(val + i);
        w[id[0]] = v[0] * VALUE_SCALE;
        w[id[1]] = v[1] * VALUE_SCALE;
        w[id[2]] = v[2] * VALUE_SCALE;
        w[id[3]] = v[3] * VALUE_SCALE;
    } else {
        for (int j = i; j < n; ++j) w[idx[j]] = val[j] * VALUE_SCALE;
    }
}

__device__ __forceinline__ void gload16(const float* src, float* ldsDst) {
    __builtin_amdgcn_global_load_lds(
        (const __attribute__((address_space(1))) void*)src,
        (__attribute__((address_space(3))) void*)ldsDst, 16, 0, 0);
}

__device__ __forceinline__ short f2bf_rn(float f) {
    return (short)__bfloat16_as_ushort(__float2bfloat16(f));
}

// ---------------- split-K bf16 GEMM: part[ks] = x @ W[ncols]^T (K-slice ks) --------
// R5 geometry: grid 512 = 2 WG/CU (the R4 fix: cross-block overlap hides the
// vmcnt(0)+barrier drain — 1 WG/CU left the whole CU stalled at every K-step barrier).
// Block 256 thr = 4 waves; wave owns 64 rows x 64 cols = 4x4 frags of 16x16.
// LDS 80KB/WG (A dbuf 64KB + B dbuf 16KB); 2 x 80KB = 160KB = full CU pool.
// fp32 tiles staged via async global_load_lds; fp32->bf16 at frag read.
// Chunk swizzle on global SOURCE address (linear LDS dest — rule #21).
__global__ __launch_bounds__(256, 2) void gemm_k(const float* __restrict__ x,
                                                 const float* __restrict__ w,
                                                 float* __restrict__ part,
                                                 float* __restrict__ y) {
    const int tid  = threadIdx.x;
    const int lane = tid & 63;
    const int wv   = tid >> 6;      // 0..3 -> rows wv*64..+64
    const int bid  = blockIdx.x;
    const int ks   = bid & 7;
    const int bn   = bid >> 3;      // 0..63
    const int k0   = ks * KPER;
    const int nc0  = bn * BN;

    __shared__ __align__(16) float At[2][BATCH * BK];  // 2 x 32KB
    __shared__ __align__(16) float Bt[2][BN * BK];     // 2 x 8KB   -> 80KB total

    f32x4 acc[4][4];
#pragma unroll
    for (int m = 0; m < 4; ++m)
#pragma unroll
        for (int n = 0; n < 4; ++n) acc[m][n] = (f32x4)0.0f;

    auto stage = [&](int buf, int t) {
        const int kg = k0 + t * BK;
        const int rsub = lane >> 3;          // 0..7 (row within 8-row group)
        const int csl  = lane & 7;           // lds chunk slot 0..7
#pragma unroll
        for (int j = 0; j < 8; ++j) {        // A: rows wv*64 .. +64
            int r0  = wv * 64 + j * 8;
            int row = r0 + rsub;
            int c   = csl ^ (row & 7);       // global chunk for this lds slot
            gload16(x + (size_t)row * IC + kg + c * 4, &At[buf][r0 * BK]);
        }
#pragma unroll
        for (int j = 0; j < 2; ++j) {        // B: rows wv*16 .. +16
            int r0  = wv * 16 + j * 8;
            int row = r0 + rsub;
            int c   = csl ^ (row & 7);
            gload16(w + (size_t)(nc0 + row) * IC + kg + c * 4, &Bt[buf][r0 * BK]);
        }
    };

    auto readFrag = [&](const float* tile, int row) -> bf16x8 {
        int c0  = (lane >> 4) * 2;           // logical chunk pair
        int cp0 = c0 ^ (row & 7);
        int cp1 = (c0 + 1) ^ (row & 7);
        const float* base = tile + row * BK;
        f32x4 lo = *(const f32x4*)(base + cp0 * 4);
        f32x4 hi = *(const f32x4*)(base + cp1 * 4);
        bf16x8 r;
#pragma unroll
        for (int j = 0; j < 4; ++j) {
            r[j]     = f2bf_rn(lo[j]);
            r[j + 4] = f2bf_rn(hi[j]);
        }
        return r;
    };

    stage(0, 0);
    __syncthreads();

    for (int t = 0; t < NT; ++t) {
        const int cur = t & 1;
        if (t + 1 < NT) stage(cur ^ 1, t + 1);

        bf16x8 a[4], b[4];
#pragma unroll
        for (int m = 0; m < 4; ++m)
            a[m] = readFrag(At[cur], wv * 64 + m * 16 + (lane & 15));
#pragma unroll
        for (int n = 0; n < 4; ++n)
            b[n] = readFrag(Bt[cur], n * 16 + (lane & 15));
#pragma unroll
        for (int n = 0; n < 4; ++n)
#pragma unroll
            for (int m = 0; m < 4; ++m)
                acc[m][n] = __builtin_amdgcn_mfma_f32_16x16x32_bf16(a[m], b[n], acc[m][n], 0, 0, 0);

        __syncthreads();
    }

    // epilogue: C/D layout col=lane&15, row=(lane>>4)*4+reg  [proven R1/R3/R4]
    if (part) {
        float* dst = part + (size_t)ks * YSZ;
#pragma unroll
        for (int m = 0; m < 4; ++m) {
            int r0 = wv * 64 + m * 16 + (lane >> 4) * 4;
#pragma unroll
            for (int n = 0; n < 4; ++n) {
                int c = nc0 + n * 16 + (lane & 15);
#pragma unroll
                for (int r = 0; r < 4; ++r)
                    dst[(size_t)(r0 + r) * OC + c] = acc[m][n][r];
            }
        }
    } else {  // fallback when ws too small: atomic path (y pre-zeroed)
#pragma unroll
        for (int m = 0; m < 4; ++m) {
            int r0 = wv * 64 + m * 16 + (lane >> 4) * 4;
#pragma unroll
            for (int n = 0; n < 4; ++n) {
                int c = nc0 + n * 16 + (lane & 15);
#pragma unroll
                for (int r = 0; r < 4; ++r)
                    atomicAdd(&y[(size_t)(r0 + r) * OC + c], acc[m][n][r]);
            }
        }
    }
}

// ---------------- reduce: y = sum of KS partial buffers (streaming, f32x4) ----------
__global__ void reduce_k(const float* __restrict__ part, float* __restrict__ y) {
    int i = (blockIdx.x * blockDim.x + threadIdx.x) * 4;
    f32x4 s = *(const f32x4*)(part + i);
#pragma unroll
    for (int p = 1; p < KS; ++p) s += *(const f32x4*)(part + (size_t)p * YSZ + i);
    *(f32x4*)(y + i) = s;
}

extern "C" void kernel_launch(void* const* d_in, const int* in_sizes, int n_in,
                              void* d_out, int out_size, void* d_ws, size_t ws_size,
                              hipStream_t stream) {
    const float* x  = (const float*)d_in[0];
    float*       w  = (float*)d_in[1];      // scattered in place (set = idempotent)
    const int*   fi = (const int*)d_in[2];
    const float* fv = (const float*)d_in[3];
    float*       y  = (float*)d_out;
    const int nflip = in_sizes[2];

    const bool use_ws = ws_size >= (size_t)KS * YSZ * sizeof(float);  // 32MB
    float* part = use_ws ? (float*)d_ws : nullptr;

    if (!use_ws) hipMemsetAsync(d_out, 0, (size_t)out_size * sizeof(float), stream);
    scatter_k<<<dim3((nflip + 1023) / 1024), dim3(256), 0, stream>>>(w, fi, fv, nflip);
    gemm_k<<<dim3((OC / BN) * KS), dim3(256), 0, stream>>>(x, w, part, y);
    if (use_ws)
        reduce_k<<<dim3(YSZ / (4 * 256)), dim3(256), 0, stream>>>(part, y);
}